// Round 1
// baseline (93.401 us; speedup 1.0000x reference)
//
#include <hip/hip_runtime.h>
#include <hip/hip_bf16.h>

// Sizes (fixed by the reference)
#define BATCH 2
#define SEQ   4096
#define DIM   256
#define HEADS 8
#define HDIM  32
#define M_ROWS (BATCH * SEQ)   // 8192

// ---------------------------------------------------------------------------
// K1: GEMM  C[8192,512] = h[8192,256] @ [W_l | W_r][256,512]  (f32, VALU)
// Tiles: BM=128 x BN=64, 256 threads, thread tile 8x4, KB=16.
// ---------------------------------------------------------------------------
#define BM 128
#define BN 64
#define KB 16
#define APAD 132   // row stride for As (132 % 32 == 4 -> 2-way max)
#define BPAD 68    // row stride for Bs

__global__ __launch_bounds__(256) void k_gemm(const float* __restrict__ A,
                                              const float* __restrict__ Wl,
                                              const float* __restrict__ Wr,
                                              float* __restrict__ fl,
                                              float* __restrict__ fr) {
  __shared__ float As[KB][APAD];
  __shared__ float Bs[KB][BPAD];

  const int bid = blockIdx.x;
  const int bn = bid & 7;        // 8 col tiles of 64 over [W_l|W_r]
  const int bm = bid >> 3;       // 64 row tiles of 128
  const float* W = (bn < 4) ? Wl : Wr;
  float* Cout    = (bn < 4) ? fl : fr;
  const int co = (bn & 3) * BN;  // col offset within 256
  const int m0 = bm * BM;

  const int t  = threadIdx.x;
  const int tx = t & 15;         // 16 cols of 4
  const int ty = t >> 4;         // 16 rows of 8

  float acc[8][4];
  #pragma unroll
  for (int i = 0; i < 8; ++i)
    #pragma unroll
    for (int j = 0; j < 4; ++j) acc[i][j] = 0.f;

  for (int k0 = 0; k0 < DIM; k0 += KB) {
    // A tile: 128 rows x 16 k = 512 float4, 2 per thread
    #pragma unroll
    for (int l = 0; l < 2; ++l) {
      const int f = t + l * 256;
      const int m = f >> 2;
      const int kq = (f & 3) * 4;
      const float4 v = *(const float4*)(&A[(size_t)(m0 + m) * DIM + k0 + kq]);
      As[kq + 0][m] = v.x; As[kq + 1][m] = v.y;
      As[kq + 2][m] = v.z; As[kq + 3][m] = v.w;
    }
    // B tile: 16 k x 64 n = 256 float4, 1 per thread
    {
      const int k = t >> 4;
      const int n = (t & 15) * 4;
      *(float4*)(&Bs[k][n]) = *(const float4*)(&W[(size_t)(k0 + k) * DIM + co + n]);
    }
    __syncthreads();
    #pragma unroll
    for (int k = 0; k < KB; ++k) {
      float a0[8], b0[4];
      *(float4*)(&a0[0]) = *(const float4*)(&As[k][ty * 8]);
      *(float4*)(&a0[4]) = *(const float4*)(&As[k][ty * 8 + 4]);
      *(float4*)(&b0[0]) = *(const float4*)(&Bs[k][tx * 4]);
      #pragma unroll
      for (int i = 0; i < 8; ++i)
        #pragma unroll
        for (int j = 0; j < 4; ++j)
          acc[i][j] = fmaf(a0[i], b0[j], acc[i][j]);
    }
    __syncthreads();
  }
  #pragma unroll
  for (int i = 0; i < 8; ++i) {
    const int m = m0 + ty * 8 + i;
    *(float4*)(&Cout[(size_t)m * DIM + co + tx * 4]) = *(float4*)(&acc[i][0]);
  }
}

// ---------------------------------------------------------------------------
// K2: per-row head scores. sl/sr = sum_d leaky(f)*a ; write sr, msl, msr.
// One block per row, 256 threads (one per dim).
// ---------------------------------------------------------------------------
__global__ __launch_bounds__(256) void k_scores(const float* __restrict__ fl,
                                                const float* __restrict__ fr,
                                                const float* __restrict__ a_l,
                                                const float* __restrict__ a_r,
                                                float* __restrict__ sr,
                                                float* __restrict__ msl,
                                                float* __restrict__ msr) {
  const int row = blockIdx.x;          // b*4096 + n
  const int t = threadIdx.x;           // dim 0..255
  const int d = t & 31;
  float vl = fl[(size_t)row * DIM + t];
  float vr = fr[(size_t)row * DIM + t];
  vl = vl >= 0.f ? vl : 0.01f * vl;
  vr = vr >= 0.f ? vr : 0.01f * vr;
  float pl = vl * a_l[d];
  float pr = vr * a_r[d];
  #pragma unroll
  for (int o = 16; o > 0; o >>= 1) {
    pl += __shfl_xor(pl, o, 32);
    pr += __shfl_xor(pr, o, 32);
  }
  __shared__ float sl_s[8], sr_s[8];
  if (d == 0) { sl_s[t >> 5] = pl; sr_s[t >> 5] = pr; }
  __syncthreads();
  if (t < 8) {
    const int b = row >> 12, n = row & 4095;
    sr[((size_t)b * HEADS + t) * SEQ + n] = sr_s[t];
  }
  if (t == 0) {
    float al = 0.f, ar2 = 0.f;
    #pragma unroll
    for (int h2 = 0; h2 < 8; ++h2) { al += sl_s[h2]; ar2 += sr_s[h2]; }
    msl[row] = al * 0.125f;
    msr[row] = ar2 * 0.125f;
  }
}

// ---------------------------------------------------------------------------
// K3: softmax over j (len 4096) for each of 16 (b,h). One block each.
// ---------------------------------------------------------------------------
__global__ __launch_bounds__(256) void k_softmax(const float* __restrict__ sr,
                                                 float* __restrict__ w) {
  const int bh = blockIdx.x;
  const float* s = sr + (size_t)bh * SEQ;
  float* ww = w + (size_t)bh * SEQ;
  const int t = threadIdx.x;
  float v[16];
  float mx = -3.4e38f;
  #pragma unroll
  for (int q = 0; q < 16; ++q) { v[q] = s[q * 256 + t]; mx = fmaxf(mx, v[q]); }
  #pragma unroll
  for (int o = 32; o > 0; o >>= 1) mx = fmaxf(mx, __shfl_xor(mx, o, 64));
  __shared__ float r1[4], r2[4];
  if ((t & 63) == 0) r1[t >> 6] = mx;
  __syncthreads();
  mx = fmaxf(fmaxf(r1[0], r1[1]), fmaxf(r1[2], r1[3]));
  float sum = 0.f;
  #pragma unroll
  for (int q = 0; q < 16; ++q) { v[q] = expf(v[q] - mx); sum += v[q]; }
  #pragma unroll
  for (int o = 32; o > 0; o >>= 1) sum += __shfl_xor(sum, o, 64);
  if ((t & 63) == 0) r2[t >> 6] = sum;
  __syncthreads();
  sum = r2[0] + r2[1] + r2[2] + r2[3];
  const float inv = 1.0f / sum;
  #pragma unroll
  for (int q = 0; q < 16; ++q) ww[q * 256 + t] = v[q] * inv;
}

// ---------------------------------------------------------------------------
// K4: context partials. c[b, t] = sum_j w[b, t/32, j] * fr[b, j, t].
// Grid: B * 64 chunks of 64 j's. Writes cpart[(b*64+jc)*256 + t].
// ---------------------------------------------------------------------------
__global__ __launch_bounds__(256) void k_context(const float* __restrict__ fr,
                                                 const float* __restrict__ w,
                                                 float* __restrict__ cpart) {
  const int b  = blockIdx.x >> 6;
  const int jc = blockIdx.x & 63;
  const int j0 = jc * 64;
  const int t = threadIdx.x;
  __shared__ float ws_[8][64];
  for (int l = t; l < 512; l += 256) {
    const int h2 = l >> 6, jj = l & 63;
    ws_[h2][jj] = w[((size_t)b * HEADS + h2) * SEQ + j0 + jj];
  }
  __syncthreads();
  const int h2 = t >> 5;
  float accv = 0.f;
  #pragma unroll 8
  for (int jj = 0; jj < 64; ++jj) {
    accv = fmaf(ws_[h2][jj], fr[((size_t)(b * SEQ + j0 + jj)) * DIM + t], accv);
  }
  cpart[(size_t)(b * 64 + jc) * DIM + t] = accv;
}

// ---------------------------------------------------------------------------
// K5: reduce cpart -> c, then fh[b,:] = c @ W_final. 2 blocks, 256 threads.
// ---------------------------------------------------------------------------
__global__ __launch_bounds__(256) void k_fh(const float* __restrict__ cpart,
                                            const float* __restrict__ Wf,
                                            float* __restrict__ fh) {
  const int b = blockIdx.x;
  const int t = threadIdx.x;
  __shared__ float c_s[DIM];
  float cv = 0.f;
  #pragma unroll 8
  for (int jc = 0; jc < 64; ++jc) cv += cpart[(size_t)(b * 64 + jc) * DIM + t];
  c_s[t] = cv;
  __syncthreads();
  float acc = 0.f;
  #pragma unroll 8
  for (int k = 0; k < DIM; ++k) acc = fmaf(c_s[k], Wf[(size_t)k * DIM + t], acc);
  fh[b * DIM + t] = acc;
}

// ---------------------------------------------------------------------------
// K6: LayerNorm(h + fh) * g + b -> out. One block per row.
// ---------------------------------------------------------------------------
__global__ __launch_bounds__(256) void k_ln(const float* __restrict__ h,
                                            const float* __restrict__ fh,
                                            const float* __restrict__ g,
                                            const float* __restrict__ bb,
                                            float* __restrict__ out) {
  const int row = blockIdx.x;
  const int b = row >> 12;
  const int t = threadIdx.x;
  const float x = h[(size_t)row * DIM + t] + fh[b * DIM + t];
  float s1 = x, s2 = x * x;
  #pragma unroll
  for (int o = 32; o > 0; o >>= 1) {
    s1 += __shfl_xor(s1, o, 64);
    s2 += __shfl_xor(s2, o, 64);
  }
  __shared__ float r1[4], r2[4];
  if ((t & 63) == 0) { r1[t >> 6] = s1; r2[t >> 6] = s2; }
  __syncthreads();
  s1 = r1[0] + r1[1] + r1[2] + r1[3];
  s2 = r2[0] + r2[1] + r2[2] + r2[3];
  const float mu = s1 * (1.f / 256.f);
  const float var = s2 * (1.f / 256.f) - mu * mu;
  const float rs = rsqrtf(var + 1e-5f);
  out[(size_t)row * DIM + t] = (x - mu) * rs * g[t] + bb[t];
}

// ---------------------------------------------------------------------------
// K7: attn[b,i,j] = msl[b,i] + msr[b,j]. One block per (b,i) row; float4.
// ---------------------------------------------------------------------------
__global__ __launch_bounds__(256) void k_attn(const float* __restrict__ msl,
                                              const float* __restrict__ msr,
                                              float* __restrict__ attn) {
  const int row = blockIdx.x;        // b*4096 + i
  const int b = row >> 12;
  const float v = msl[row];
  const float4* mr = (const float4*)(msr + ((size_t)b << 12));
  float4* dst = (float4*)(attn + ((size_t)row << 12));
  const int t = threadIdx.x;
  #pragma unroll
  for (int q = 0; q < 4; ++q) {
    const float4 m4 = mr[q * 256 + t];
    dst[q * 256 + t] = make_float4(v + m4.x, v + m4.y, v + m4.z, v + m4.w);
  }
}

// ---------------------------------------------------------------------------
extern "C" void kernel_launch(void* const* d_in, const int* in_sizes, int n_in,
                              void* d_out, int out_size, void* d_ws, size_t ws_size,
                              hipStream_t stream) {
  const float* h  = (const float*)d_in[0];
  const float* Wl = (const float*)d_in[1];
  const float* Wr = (const float*)d_in[2];
  const float* al = (const float*)d_in[3];
  const float* ar = (const float*)d_in[4];
  const float* Wf = (const float*)d_in[5];
  const float* g  = (const float*)d_in[6];
  const float* bb = (const float*)d_in[7];
  float* out = (float*)d_out;
  float* ws  = (float*)d_ws;

  float* fl    = ws;                         // 2,097,152
  float* fr    = fl + (size_t)M_ROWS * DIM;  // 2,097,152
  float* srs   = fr + (size_t)M_ROWS * DIM;  // 65,536
  float* msl   = srs + BATCH * HEADS * SEQ;  // 8,192
  float* msr   = msl + M_ROWS;               // 8,192
  float* wsm   = msr + M_ROWS;               // 65,536
  float* cpart = wsm + BATCH * HEADS * SEQ;  // 32,768
  float* fh    = cpart + BATCH * 64 * DIM;   // 512

  k_gemm<<<512, 256, 0, stream>>>(h, Wl, Wr, fl, fr);
  k_scores<<<M_ROWS, 256, 0, stream>>>(fl, fr, al, ar, srs, msl, msr);
  k_softmax<<<BATCH * HEADS, 256, 0, stream>>>(srs, wsm);
  k_context<<<BATCH * 64, 256, 0, stream>>>(fr, wsm, cpart);
  k_fh<<<BATCH, 256, 0, stream>>>(cpart, Wf, fh);
  k_ln<<<M_ROWS, 256, 0, stream>>>(h, fh, g, bb, out);
  k_attn<<<M_ROWS, 256, 0, stream>>>(msl, msr, out + (size_t)M_ROWS * DIM);
}

// Round 2
// 77.763 us; speedup vs baseline: 1.2011x; 1.2011x over previous
//
#include <hip/hip_runtime.h>
#include <hip/hip_bf16.h>

// Sizes (fixed by the reference)
#define BATCH 2
#define SEQ   4096
#define DIM   256
#define HEADS 8
#define HDIM  32
#define M_ROWS (BATCH * SEQ)   // 8192

typedef short bf16x8 __attribute__((ext_vector_type(8)));
typedef unsigned short u16x8 __attribute__((ext_vector_type(8)));
typedef float f32x4 __attribute__((ext_vector_type(4)));

static __device__ inline unsigned short f2bf(float x) {
  union { float f; unsigned u; } v; v.f = x;
  unsigned r = v.u + 0x7FFF + ((v.u >> 16) & 1);   // round-nearest-even
  return (unsigned short)(r >> 16);
}

// ---------------------------------------------------------------------------
// K0: prep — Wt[n][k] = bf16(Wcat[k][n]), n in [0,512) over [Wl|Wr].
// grid (8 k-tiles, 16 n-tiles) x 256 threads; 32x32 tile transpose via LDS.
// ---------------------------------------------------------------------------
__global__ __launch_bounds__(256) void k_prep(const float* __restrict__ Wl,
                                              const float* __restrict__ Wr,
                                              unsigned short* __restrict__ Wt) {
  __shared__ float tile[32][33];
  const int k0 = blockIdx.x * 32;
  const int n0 = blockIdx.y * 32;
  const int t = threadIdx.x;
  const float* W = (n0 < 256) ? Wl : Wr;
  const int nb = n0 & 255;
  {
    const int r = t >> 3;            // k-local
    const int c = (t & 7) * 4;       // n-local
    const float4 v = *(const float4*)(&W[(size_t)(k0 + r) * DIM + nb + c]);
    tile[r][c + 0] = v.x; tile[r][c + 1] = v.y;
    tile[r][c + 2] = v.z; tile[r][c + 3] = v.w;
  }
  __syncthreads();
  {
    const int nl = t >> 3;           // n-local
    const int kl = (t & 7) * 4;      // k-local
    ushort4 o;
    o.x = f2bf(tile[kl + 0][nl]); o.y = f2bf(tile[kl + 1][nl]);
    o.z = f2bf(tile[kl + 2][nl]); o.w = f2bf(tile[kl + 3][nl]);
    *(ushort4*)(&Wt[(size_t)(n0 + nl) * DIM + k0 + kl]) = o;
  }
}

// ---------------------------------------------------------------------------
// K1: MFMA GEMM  [fl|fr][8192,512] = h[8192,256] @ Wcat[256,512] in bf16.
// 128x128 tile, 4 waves (2x2), 16x16x32 bf16 MFMA, BK=32, 8 K-steps.
// LDS As/Bs [128 rows][32 k] bf16, 16B-slot XOR swizzle: slot ^= (row>>1)&3.
// ---------------------------------------------------------------------------
__global__ __launch_bounds__(256) void k_gemm_mfma(const float* __restrict__ A,
                                                   const unsigned short* __restrict__ Wt,
                                                   float* __restrict__ fl,
                                                   float* __restrict__ fr) {
  __shared__ unsigned short As[128 * 32];
  __shared__ unsigned short Bs[128 * 32];

  const int bid = blockIdx.x;      // 256 blocks
  const int bn = bid & 3;          // 4 col tiles of 128 over 512
  const int bm = bid >> 2;         // 64 row tiles of 128
  const int m0 = bm * 128;
  const int n0 = bn * 128;

  const int t = threadIdx.x;
  const int lane = t & 63;
  const int wid = t >> 6;
  const int wr = wid >> 1;         // wave row 0..1 (64 rows each)
  const int wc = wid & 1;          // wave col 0..1 (64 cols each)

  f32x4 acc[4][4];
  #pragma unroll
  for (int i = 0; i < 4; ++i)
    #pragma unroll
    for (int j = 0; j < 4; ++j) acc[i][j] = (f32x4){0.f, 0.f, 0.f, 0.f};

  // staging coords: 4 threads per row, each covers 8 elements (one 16B slot)
  const int srow = t >> 2;         // 0..63 (+64 on pass 1)
  const int kc   = t & 3;          // 16B slot index 0..3

  for (int k0 = 0; k0 < DIM; k0 += 32) {
    #pragma unroll
    for (int p = 0; p < 2; ++p) {
      const int row = srow + p * 64;
      const int slot = kc ^ ((row >> 1) & 3);
      // A: load 8 f32, convert, store one 16B packet
      const float4 a0 = *(const float4*)(&A[(size_t)(m0 + row) * DIM + k0 + kc * 8]);
      const float4 a1 = *(const float4*)(&A[(size_t)(m0 + row) * DIM + k0 + kc * 8 + 4]);
      u16x8 pa;
      pa[0] = f2bf(a0.x); pa[1] = f2bf(a0.y); pa[2] = f2bf(a0.z); pa[3] = f2bf(a0.w);
      pa[4] = f2bf(a1.x); pa[5] = f2bf(a1.y); pa[6] = f2bf(a1.z); pa[7] = f2bf(a1.w);
      *(u16x8*)((char*)As + row * 64 + slot * 16) = pa;
      // B: already bf16 in Wt, rows of Wt = cols of W
      const u16x8 pb = *(const u16x8*)(&Wt[(size_t)(n0 + row) * DIM + k0 + kc * 8]);
      *(u16x8*)((char*)Bs + row * 64 + slot * 16) = pb;
    }
    __syncthreads();

    bf16x8 af[4], bfr[4];
    #pragma unroll
    for (int mr = 0; mr < 4; ++mr) {
      const int ra = wr * 64 + mr * 16 + (lane & 15);
      const int sl = (lane >> 4) ^ ((ra >> 1) & 3);
      af[mr] = *(const bf16x8*)((const char*)As + ra * 64 + sl * 16);
    }
    #pragma unroll
    for (int nr = 0; nr < 4; ++nr) {
      const int cb = wc * 64 + nr * 16 + (lane & 15);
      const int sl = (lane >> 4) ^ ((cb >> 1) & 3);
      bfr[nr] = *(const bf16x8*)((const char*)Bs + cb * 64 + sl * 16);
    }
    #pragma unroll
    for (int mr = 0; mr < 4; ++mr)
      #pragma unroll
      for (int nr = 0; nr < 4; ++nr)
        acc[mr][nr] = __builtin_amdgcn_mfma_f32_16x16x32_bf16(af[mr], bfr[nr], acc[mr][nr], 0, 0, 0);
    __syncthreads();
  }

  // epilogue: C/D layout col=lane&15, row=(lane>>4)*4+reg
  float* Cout = (n0 < 256) ? fl : fr;
  const int cbase = n0 & 255;
  #pragma unroll
  for (int mr = 0; mr < 4; ++mr)
    #pragma unroll
    for (int nr = 0; nr < 4; ++nr) {
      const int col = cbase + wc * 64 + nr * 16 + (lane & 15);
      #pragma unroll
      for (int r = 0; r < 4; ++r) {
        const int row = m0 + wr * 64 + mr * 16 + (lane >> 4) * 4 + r;
        Cout[(size_t)row * DIM + col] = acc[mr][nr][r];
      }
    }
}

// ---------------------------------------------------------------------------
// K2: per-row head scores. sl/sr = sum_d leaky(f)*a ; write sr, msl, msr.
// ---------------------------------------------------------------------------
__global__ __launch_bounds__(256) void k_scores(const float* __restrict__ fl,
                                                const float* __restrict__ fr,
                                                const float* __restrict__ a_l,
                                                const float* __restrict__ a_r,
                                                float* __restrict__ sr,
                                                float* __restrict__ msl,
                                                float* __restrict__ msr) {
  const int row = blockIdx.x;          // b*4096 + n
  const int t = threadIdx.x;           // dim 0..255
  const int d = t & 31;
  float vl = fl[(size_t)row * DIM + t];
  float vr = fr[(size_t)row * DIM + t];
  vl = vl >= 0.f ? vl : 0.01f * vl;
  vr = vr >= 0.f ? vr : 0.01f * vr;
  float pl = vl * a_l[d];
  float pr = vr * a_r[d];
  #pragma unroll
  for (int o = 16; o > 0; o >>= 1) {
    pl += __shfl_xor(pl, o, 32);
    pr += __shfl_xor(pr, o, 32);
  }
  __shared__ float sl_s[8], sr_s[8];
  if (d == 0) { sl_s[t >> 5] = pl; sr_s[t >> 5] = pr; }
  __syncthreads();
  if (t < 8) {
    const int b = row >> 12, n = row & 4095;
    sr[((size_t)b * HEADS + t) * SEQ + n] = sr_s[t];
  }
  if (t == 0) {
    float al = 0.f, ar2 = 0.f;
    #pragma unroll
    for (int h2 = 0; h2 < 8; ++h2) { al += sl_s[h2]; ar2 += sr_s[h2]; }
    msl[row] = al * 0.125f;
    msr[row] = ar2 * 0.125f;
  }
}

// ---------------------------------------------------------------------------
// K3: softmax over j (len 4096) for each of 16 (b,h). One block each.
// ---------------------------------------------------------------------------
__global__ __launch_bounds__(256) void k_softmax(const float* __restrict__ sr,
                                                 float* __restrict__ w) {
  const int bh = blockIdx.x;
  const float* s = sr + (size_t)bh * SEQ;
  float* ww = w + (size_t)bh * SEQ;
  const int t = threadIdx.x;
  float v[16];
  float mx = -3.4e38f;
  #pragma unroll
  for (int q = 0; q < 16; ++q) { v[q] = s[q * 256 + t]; mx = fmaxf(mx, v[q]); }
  #pragma unroll
  for (int o = 32; o > 0; o >>= 1) mx = fmaxf(mx, __shfl_xor(mx, o, 64));
  __shared__ float r1[4], r2[4];
  if ((t & 63) == 0) r1[t >> 6] = mx;
  __syncthreads();
  mx = fmaxf(fmaxf(r1[0], r1[1]), fmaxf(r1[2], r1[3]));
  float sum = 0.f;
  #pragma unroll
  for (int q = 0; q < 16; ++q) { v[q] = expf(v[q] - mx); sum += v[q]; }
  #pragma unroll
  for (int o = 32; o > 0; o >>= 1) sum += __shfl_xor(sum, o, 64);
  if ((t & 63) == 0) r2[t >> 6] = sum;
  __syncthreads();
  sum = r2[0] + r2[1] + r2[2] + r2[3];
  const float inv = 1.0f / sum;
  #pragma unroll
  for (int q = 0; q < 16; ++q) ww[q * 256 + t] = v[q] * inv;
}

// ---------------------------------------------------------------------------
// K4: context partials. c[b, t] = sum_j w[b, t/32, j] * fr[b, j, t].
// ---------------------------------------------------------------------------
__global__ __launch_bounds__(256) void k_context(const float* __restrict__ fr,
                                                 const float* __restrict__ w,
                                                 float* __restrict__ cpart) {
  const int b  = blockIdx.x >> 6;
  const int jc = blockIdx.x & 63;
  const int j0 = jc * 64;
  const int t = threadIdx.x;
  __shared__ float ws_[8][64];
  for (int l = t; l < 512; l += 256) {
    const int h2 = l >> 6, jj = l & 63;
    ws_[h2][jj] = w[((size_t)b * HEADS + h2) * SEQ + j0 + jj];
  }
  __syncthreads();
  const int h2 = t >> 5;
  float accv = 0.f;
  #pragma unroll 8
  for (int jj = 0; jj < 64; ++jj) {
    accv = fmaf(ws_[h2][jj], fr[((size_t)(b * SEQ + j0 + jj)) * DIM + t], accv);
  }
  cpart[(size_t)(b * 64 + jc) * DIM + t] = accv;
}

// ---------------------------------------------------------------------------
// K5: reduce cpart -> c, then fh[b,:] = c @ W_final. 2 blocks, 256 threads.
// ---------------------------------------------------------------------------
__global__ __launch_bounds__(256) void k_fh(const float* __restrict__ cpart,
                                            const float* __restrict__ Wf,
                                            float* __restrict__ fh) {
  const int b = blockIdx.x;
  const int t = threadIdx.x;
  __shared__ float c_s[DIM];
  float cv = 0.f;
  #pragma unroll 8
  for (int jc = 0; jc < 64; ++jc) cv += cpart[(size_t)(b * 64 + jc) * DIM + t];
  c_s[t] = cv;
  __syncthreads();
  float acc = 0.f;
  #pragma unroll 8
  for (int k = 0; k < DIM; ++k) acc = fmaf(c_s[k], Wf[(size_t)k * DIM + t], acc);
  fh[b * DIM + t] = acc;
}

// ---------------------------------------------------------------------------
// K6: LayerNorm(h + fh) * g + b -> out. One block per row.
// ---------------------------------------------------------------------------
__global__ __launch_bounds__(256) void k_ln(const float* __restrict__ h,
                                            const float* __restrict__ fh,
                                            const float* __restrict__ g,
                                            const float* __restrict__ bb,
                                            float* __restrict__ out) {
  const int row = blockIdx.x;
  const int b = row >> 12;
  const int t = threadIdx.x;
  const float x = h[(size_t)row * DIM + t] + fh[b * DIM + t];
  float s1 = x, s2 = x * x;
  #pragma unroll
  for (int o = 32; o > 0; o >>= 1) {
    s1 += __shfl_xor(s1, o, 64);
    s2 += __shfl_xor(s2, o, 64);
  }
  __shared__ float r1[4], r2[4];
  if ((t & 63) == 0) { r1[t >> 6] = s1; r2[t >> 6] = s2; }
  __syncthreads();
  s1 = r1[0] + r1[1] + r1[2] + r1[3];
  s2 = r2[0] + r2[1] + r2[2] + r2[3];
  const float mu = s1 * (1.f / 256.f);
  const float var = s2 * (1.f / 256.f) - mu * mu;
  const float rs = rsqrtf(var + 1e-5f);
  out[(size_t)row * DIM + t] = (x - mu) * rs * g[t] + bb[t];
}

// ---------------------------------------------------------------------------
// K7: attn[b,i,j] = msl[b,i] + msr[b,j]. One block per (b,i) row; float4.
// ---------------------------------------------------------------------------
__global__ __launch_bounds__(256) void k_attn(const float* __restrict__ msl,
                                              const float* __restrict__ msr,
                                              float* __restrict__ attn) {
  const int row = blockIdx.x;        // b*4096 + i
  const int b = row >> 12;
  const float v = msl[row];
  const float4* mr = (const float4*)(msr + ((size_t)b << 12));
  float4* dst = (float4*)(attn + ((size_t)row << 12));
  const int t = threadIdx.x;
  #pragma unroll
  for (int q = 0; q < 4; ++q) {
    const float4 m4 = mr[q * 256 + t];
    dst[q * 256 + t] = make_float4(v + m4.x, v + m4.y, v + m4.z, v + m4.w);
  }
}

// ---------------------------------------------------------------------------
extern "C" void kernel_launch(void* const* d_in, const int* in_sizes, int n_in,
                              void* d_out, int out_size, void* d_ws, size_t ws_size,
                              hipStream_t stream) {
  const float* h  = (const float*)d_in[0];
  const float* Wl = (const float*)d_in[1];
  const float* Wr = (const float*)d_in[2];
  const float* al = (const float*)d_in[3];
  const float* ar = (const float*)d_in[4];
  const float* Wf = (const float*)d_in[5];
  const float* g  = (const float*)d_in[6];
  const float* bb = (const float*)d_in[7];
  float* out = (float*)d_out;
  float* ws  = (float*)d_ws;

  float* fl    = ws;                         // 2,097,152
  float* fr    = fl + (size_t)M_ROWS * DIM;  // 2,097,152
  float* srs   = fr + (size_t)M_ROWS * DIM;  // 65,536
  float* msl   = srs + BATCH * HEADS * SEQ;  // 8,192
  float* msr   = msl + M_ROWS;               // 8,192
  float* wsm   = msr + M_ROWS;               // 65,536
  float* cpart = wsm + BATCH * HEADS * SEQ;  // 32,768
  float* fh    = cpart + BATCH * 64 * DIM;   // 512
  unsigned short* Wt = (unsigned short*)(fh + BATCH * DIM); // 512*256 u16 = 256KB

  k_prep<<<dim3(8, 16), 256, 0, stream>>>(Wl, Wr, Wt);
  k_gemm_mfma<<<256, 256, 0, stream>>>(h, Wt, fl, fr);
  k_scores<<<M_ROWS, 256, 0, stream>>>(fl, fr, al, ar, srs, msl, msr);
  k_softmax<<<BATCH * HEADS, 256, 0, stream>>>(srs, wsm);
  k_context<<<BATCH * 64, 256, 0, stream>>>(fr, wsm, cpart);
  k_fh<<<BATCH, 256, 0, stream>>>(cpart, Wf, fh);
  k_ln<<<M_ROWS, 256, 0, stream>>>(h, fh, g, bb, out);
  k_attn<<<M_ROWS, 256, 0, stream>>>(msl, msr, out + (size_t)M_ROWS * DIM);
}